// Round 1
// baseline (259.300 us; speedup 1.0000x reference)
//
#include <hip/hip_runtime.h>
#include <hip/hip_bf16.h>
#include <stdint.h>

#define NDIM 4096
#define BM 128
#define BN 128
#define BK 32

typedef __attribute__((ext_vector_type(8))) short bf16x8;
typedef __attribute__((ext_vector_type(4))) float f32x4;

__device__ __forceinline__ unsigned short f2bf(float f) {
    union { float f; uint32_t u; } v; v.f = f;
    uint32_t u = v.u;
    u += 0x7FFFu + ((u >> 16) & 1u);   // round-to-nearest-even
    return (unsigned short)(u >> 16);
}

// --- Kernel 1: A (fp32 row-major) -> triu-masked bf16 row-major ---
__global__ __launch_bounds__(256) void convA_kernel(const float* __restrict__ A,
                                                    unsigned short* __restrict__ Abf) {
    int idx = (blockIdx.x * 256 + threadIdx.x) * 4;
    int row = idx >> 12;          // /4096
    int col = idx & 4095;
    float4 v = *(const float4*)(A + idx);
    ushort4 o;
    o.x = (col + 0 >= row) ? f2bf(v.x) : (unsigned short)0;
    o.y = (col + 1 >= row) ? f2bf(v.y) : (unsigned short)0;
    o.z = (col + 2 >= row) ? f2bf(v.z) : (unsigned short)0;
    o.w = (col + 3 >= row) ? f2bf(v.w) : (unsigned short)0;
    *(ushort4*)(Abf + idx) = o;
}

// --- Kernel 2: B (fp32 row-major [k][col]) -> triu-masked bf16 transposed Bt[col][k] ---
__global__ __launch_bounds__(256) void convB_kernel(const float* __restrict__ B,
                                                    unsigned short* __restrict__ Bt) {
    __shared__ float tile[32][33];   // +1 pad: conflict-free transposed reads
    int tx = threadIdx.x, ty = threadIdx.y;
    int col = blockIdx.x * 32 + tx;          // column of B (coalesced read)
    int k0  = blockIdx.y * 32;               // k-row block of B
    #pragma unroll
    for (int i = ty; i < 32; i += 8)
        tile[i][tx] = B[(size_t)(k0 + i) * NDIM + col];
    __syncthreads();
    int k = k0 + tx;                          // inner (contiguous) dim of Bt
    #pragma unroll
    for (int i = ty; i < 32; i += 8) {
        int c = blockIdx.x * 32 + i;          // row of Bt = column of B
        // triu(B): B[k][c] kept iff c >= k
        unsigned short o = (k <= c) ? f2bf(tile[tx][i]) : (unsigned short)0;
        Bt[(size_t)c * NDIM + k] = o;
    }
}

// --- Kernel 3: triangular bf16 MFMA GEMM, m97 structure ---
// Block = 256 threads = 4 waves (2x2), each wave 64x64 = 4x4 MFMA 16x16x32 tiles.
// 1-D grid of 1024 blocks: [0,528) = upper tiles ordered by descending K-length,
// [528,1024) = strictly-lower tiles that just write zeros.
__global__ __launch_bounds__(256, 3) void trigemm_kernel(
        const unsigned short* __restrict__ Abf,
        const unsigned short* __restrict__ Bt,
        float* __restrict__ C) {
    int l = blockIdx.x;
    int bi, bj;
    if (l >= 528) {
        // strictly-lower tile: zero-fill and exit
        int t = l - 528;                      // 0..495
        int bi_ = 1, base = 0;
        while (t >= base + bi_) { base += bi_; ++bi_; }
        bi = bi_; bj = t - base;              // bi in [1,31], bj < bi
        float* Cp = C + (size_t)(bi * BM) * NDIM + bj * BN;
        float4 z = {0.f, 0.f, 0.f, 0.f};
        int tid = threadIdx.x;
        #pragma unroll
        for (int it = 0; it < 16; ++it) {
            int off = (it * 256 + tid) * 4;   // 0..16383 floats in the 128x128 tile
            int r = off >> 7, c = off & 127;
            *(float4*)(Cp + (size_t)r * NDIM + c) = z;
        }
        return;
    }
    // upper tile, descending d = bj - bi (longest K first)
    {
        int d = 31, base = 0;
        while (l >= base + (32 - d)) { base += 32 - d; --d; }
        bi = l - base; bj = bi + d;
    }

    __shared__ unsigned short As[BM * BK];    // 8 KB, [row][k] row-major
    __shared__ unsigned short Bs[BN * BK];    // 8 KB, [n][k]  (Bt layout)

    const int tid  = threadIdx.x;
    const int wave = tid >> 6, lane = tid & 63;
    const int wm = wave >> 1, wn = wave & 1;  // 2x2 wave grid
    const int m_l = lane & 15, kh = lane >> 4;

    f32x4 acc[4][4] = {};

    const int i0 = bi * BM, j0 = bj * BN;
    const int k_lo = i0;
    const int k_hi = (j0 + BN > NDIM) ? NDIM : (j0 + BN);

    const unsigned short* Ar = Abf + (size_t)i0 * NDIM;
    const unsigned short* Br = Bt  + (size_t)j0 * NDIM;

    for (int k0 = k_lo; k0 < k_hi; k0 += BK) {
        // stage A-tile (128x32 bf16 = 8 KB) and B-tile via global_load_lds width=16
        #pragma unroll
        for (int it = 0; it < 2; ++it) {
            int e   = (it * 256 + tid) * 8;   // bf16-element offset in tile (16 B/lane)
            int row = e >> 5;                 // /32
            int kc  = e & 31;
            __builtin_amdgcn_global_load_lds(
                (const __attribute__((address_space(1))) void*)(Ar + (size_t)row * NDIM + k0 + kc),
                (__attribute__((address_space(3))) void*)(&As[e]), 16, 0, 0);
            __builtin_amdgcn_global_load_lds(
                (const __attribute__((address_space(1))) void*)(Br + (size_t)row * NDIM + k0 + kc),
                (__attribute__((address_space(3))) void*)(&Bs[e]), 16, 0, 0);
        }
        __syncthreads();

        bf16x8 af[4], bfr[4];
        #pragma unroll
        for (int mt = 0; mt < 4; ++mt)
            af[mt] = *(const bf16x8*)&As[(wm * 64 + mt * 16 + m_l) * BK + kh * 8];
        #pragma unroll
        for (int nt = 0; nt < 4; ++nt)
            bfr[nt] = *(const bf16x8*)&Bs[(wn * 64 + nt * 16 + m_l) * BK + kh * 8];

        #pragma unroll
        for (int mt = 0; mt < 4; ++mt)
            #pragma unroll
            for (int nt = 0; nt < 4; ++nt)
                acc[mt][nt] = __builtin_amdgcn_mfma_f32_16x16x32_bf16(
                    af[mt], bfr[nt], acc[mt][nt], 0, 0, 0);
        __syncthreads();
    }

    // Epilogue: C/D layout col=lane&15, row=(lane>>4)*4+reg (m89/m91-verified)
    float* Crow = C + (size_t)i0 * NDIM + j0;
    #pragma unroll
    for (int mt = 0; mt < 4; ++mt) {
        #pragma unroll
        for (int nt = 0; nt < 4; ++nt) {
            #pragma unroll
            for (int r = 0; r < 4; ++r) {
                int row = wm * 64 + mt * 16 + kh * 4 + r;
                int col = wn * 64 + nt * 16 + m_l;
                float v = ((i0 + row) <= (j0 + col)) ? acc[mt][nt][r] : 0.0f;
                Crow[(size_t)row * NDIM + col] = v;
            }
        }
    }
}

extern "C" void kernel_launch(void* const* d_in, const int* in_sizes, int n_in,
                              void* d_out, int out_size, void* d_ws, size_t ws_size,
                              hipStream_t stream) {
    const float* A = (const float*)d_in[0];
    const float* B = (const float*)d_in[1];
    float* C = (float*)d_out;

    unsigned short* Abf = (unsigned short*)d_ws;                   // 32 MB
    unsigned short* Bt  = Abf + (size_t)NDIM * NDIM;               // 32 MB

    // A -> masked bf16 (16.78M elems / 4 per thread / 256 per block)
    convA_kernel<<<(NDIM * (size_t)NDIM) / (256 * 4), 256, 0, stream>>>(A, Abf);
    // B -> masked, transposed bf16
    convB_kernel<<<dim3(NDIM / 32, NDIM / 32), dim3(32, 8), 0, stream>>>(B, Bt);
    // triangular GEMM over 32x32 grid of 128x128 tiles (1024 blocks, 1-D ordered)
    trigemm_kernel<<<1024, 256, 0, stream>>>(Abf, Bt, C);
}

// Round 2
// 250.246 us; speedup vs baseline: 1.0362x; 1.0362x over previous
//
#include <hip/hip_runtime.h>
#include <hip/hip_bf16.h>
#include <stdint.h>

#define NDIM 4096
#define BM 128
#define BN 128
#define BK 32

typedef __attribute__((ext_vector_type(8))) short bf16x8;
typedef __attribute__((ext_vector_type(8))) unsigned short u16x8;
typedef __attribute__((ext_vector_type(4))) float f32x4;

__device__ __forceinline__ unsigned short f2bf(float f) {
    union { float f; uint32_t u; } v; v.f = f;
    uint32_t u = v.u;
    u += 0x7FFFu + ((u >> 16) & 1u);   // round-to-nearest-even
    return (unsigned short)(u >> 16);
}

// --- Fused prep kernel ---
// blocks [0,8192):      A (fp32) -> triu-masked bf16 row-major, 8 elems/thread
// blocks [8192,16384):  B (fp32 [k][c]) -> triu-masked bf16 transposed Bt[c][k], 64k x 32c tiles
// blocks [16384,32768): C zero-fill (harness poisons d_out with 0xAA)
__global__ __launch_bounds__(256) void prep_kernel(const float* __restrict__ A,
                                                   const float* __restrict__ B,
                                                   unsigned short* __restrict__ Abf,
                                                   unsigned short* __restrict__ Bt,
                                                   float* __restrict__ C) {
    __shared__ float lds[32 * 65];   // Bt transpose staging, pad 65 (bank-free)
    const int b   = blockIdx.x;
    const int tid = threadIdx.x;

    if (b < 8192) {
        // ---- A convert: 8 contiguous elems per thread ----
        int idx = (b * 256 + tid) * 8;
        int row = idx >> 12;
        int col = idx & 4095;
        float4 v0 = *(const float4*)(A + idx);
        float4 v1 = *(const float4*)(A + idx + 4);
        u16x8 o;
        o[0] = (col + 0 >= row) ? f2bf(v0.x) : (unsigned short)0;
        o[1] = (col + 1 >= row) ? f2bf(v0.y) : (unsigned short)0;
        o[2] = (col + 2 >= row) ? f2bf(v0.z) : (unsigned short)0;
        o[3] = (col + 3 >= row) ? f2bf(v0.w) : (unsigned short)0;
        o[4] = (col + 4 >= row) ? f2bf(v1.x) : (unsigned short)0;
        o[5] = (col + 5 >= row) ? f2bf(v1.y) : (unsigned short)0;
        o[6] = (col + 6 >= row) ? f2bf(v1.z) : (unsigned short)0;
        o[7] = (col + 7 >= row) ? f2bf(v1.w) : (unsigned short)0;
        *(u16x8*)(Abf + idx) = o;
    } else if (b < 16384) {
        // ---- B transpose+convert: tile = 64 k-rows x 32 c-cols ----
        int tb = b - 8192;
        int c0 = (tb & 127) * 32;          // 128 c-tiles
        int k0 = (tb >> 7) * 64;           // 64 k-tiles
        // load: 2 passes of 32 rows; 8 float4 per row
        #pragma unroll
        for (int p = 0; p < 2; ++p) {
            int kr = p * 32 + (tid >> 3);
            int cc = (tid & 7) * 4;
            float4 v = *(const float4*)(B + (size_t)(k0 + kr) * NDIM + c0 + cc);
            lds[(cc + 0) * 65 + kr] = v.x;
            lds[(cc + 1) * 65 + kr] = v.y;
            lds[(cc + 2) * 65 + kr] = v.z;
            lds[(cc + 3) * 65 + kr] = v.w;
        }
        __syncthreads();
        // store: each thread one ushort8 (8 consecutive k for one c)
        int c  = tid >> 3;
        int ks = (tid & 7) * 8;
        u16x8 o;
        #pragma unroll
        for (int j = 0; j < 8; ++j) {
            float f = lds[c * 65 + ks + j];
            // triu(B): keep B[k][c] iff k <= c
            o[j] = (k0 + ks + j <= c0 + c) ? f2bf(f) : (unsigned short)0;
        }
        *(u16x8*)(Bt + (size_t)(c0 + c) * NDIM + k0 + ks) = o;
    } else {
        // ---- C zero ----
        int idx = ((b - 16384) * 256 + tid) * 4;
        float4 z = {0.f, 0.f, 0.f, 0.f};
        *(float4*)(C + idx) = z;
    }
}

// --- Triangular bf16 MFMA GEMM, m97 structure + split-K (chunk <= 32 k-iters) ---
// Grid = 1000 chunks. Group by d = bj-bi descending; nsplit(d) = ceil((d+1)/8).
// Chunks with nsplit==1 plain-store; others atomicAdd into zeroed C.
__global__ __launch_bounds__(256, 3) void trigemm_kernel(
        const unsigned short* __restrict__ Abf,
        const unsigned short* __restrict__ Bt,
        float* __restrict__ C) {
    // decode blockIdx -> (d, tile, split)
    int rem = blockIdx.x;
    int d = 31, nsplit = 4;
    for (;; --d) {
        nsplit = (d + 8) >> 3;             // ceil((d+1)/8)
        int cnt = (32 - d) * nsplit;
        if (rem < cnt) break;
        rem -= cnt;
    }
    const int bi = rem / nsplit;
    const int split = rem - bi * nsplit;
    const int bj = bi + d;

    __shared__ unsigned short As[BM * BK];    // 8 KB, [row][k]
    __shared__ unsigned short Bs[BN * BK];    // 8 KB, [n][k]

    const int tid  = threadIdx.x;
    const int wave = tid >> 6, lane = tid & 63;
    const int wm = wave >> 1, wn = wave & 1;
    const int m_l = lane & 15, kh = lane >> 4;

    f32x4 acc[4][4] = {};

    const int i0 = bi * BM, j0 = bj * BN;
    const int kiters_tile = (d + 1) * 4;                   // total 32-elem steps
    const int it0 = split * 32;
    int nit = kiters_tile - it0; if (nit > 32) nit = 32;
    const int k_start = i0 + it0 * BK;

    const unsigned short* Ar = Abf + (size_t)i0 * NDIM;
    const unsigned short* Br = Bt  + (size_t)j0 * NDIM;

    for (int it = 0; it < nit; ++it) {
        const int k0 = k_start + it * BK;
        #pragma unroll
        for (int pass = 0; pass < 2; ++pass) {
            int e   = (pass * 256 + tid) * 8;   // bf16 elem offset (16 B/lane)
            int row = e >> 5;
            int kc  = e & 31;
            __builtin_amdgcn_global_load_lds(
                (const __attribute__((address_space(1))) void*)(Ar + (size_t)row * NDIM + k0 + kc),
                (__attribute__((address_space(3))) void*)(&As[e]), 16, 0, 0);
            __builtin_amdgcn_global_load_lds(
                (const __attribute__((address_space(1))) void*)(Br + (size_t)row * NDIM + k0 + kc),
                (__attribute__((address_space(3))) void*)(&Bs[e]), 16, 0, 0);
        }
        __syncthreads();

        bf16x8 af[4], bfr[4];
        #pragma unroll
        for (int mt = 0; mt < 4; ++mt)
            af[mt] = *(const bf16x8*)&As[(wm * 64 + mt * 16 + m_l) * BK + kh * 8];
        #pragma unroll
        for (int nt = 0; nt < 4; ++nt)
            bfr[nt] = *(const bf16x8*)&Bs[(wn * 64 + nt * 16 + m_l) * BK + kh * 8];

        #pragma unroll
        for (int mt = 0; mt < 4; ++mt)
            #pragma unroll
            for (int nt = 0; nt < 4; ++nt)
                acc[mt][nt] = __builtin_amdgcn_mfma_f32_16x16x32_bf16(
                    af[mt], bfr[nt], acc[mt][nt], 0, 0, 0);
        __syncthreads();
    }

    // Epilogue: C/D layout col=lane&15, row=(lane>>4)*4+reg (m89/m91-verified).
    // Inputs are triu-masked, so below-diagonal accumulators are exactly 0 —
    // no mask needed. C pre-zeroed; single-split tiles can plain-store.
    float* Crow = C + (size_t)i0 * NDIM + j0;
    const bool single = (nsplit == 1);
    #pragma unroll
    for (int mt = 0; mt < 4; ++mt) {
        #pragma unroll
        for (int nt = 0; nt < 4; ++nt) {
            #pragma unroll
            for (int r = 0; r < 4; ++r) {
                int row = wm * 64 + mt * 16 + kh * 4 + r;
                int col = wn * 64 + nt * 16 + m_l;
                float* p = Crow + (size_t)row * NDIM + col;
                if (single) *p = acc[mt][nt][r];
                else        atomicAdd(p, acc[mt][nt][r]);
            }
        }
    }
}

extern "C" void kernel_launch(void* const* d_in, const int* in_sizes, int n_in,
                              void* d_out, int out_size, void* d_ws, size_t ws_size,
                              hipStream_t stream) {
    const float* A = (const float*)d_in[0];
    const float* B = (const float*)d_in[1];
    float* C = (float*)d_out;

    unsigned short* Abf = (unsigned short*)d_ws;                   // 32 MB
    unsigned short* Bt  = Abf + (size_t)NDIM * NDIM;               // 32 MB

    // Fused prep: A-convert (8192) + B-transpose (8192) + C-zero (16384)
    prep_kernel<<<32768, 256, 0, stream>>>(A, B, Abf, Bt, C);
    // Split-K triangular GEMM: 1000 chunks, <=32 k-iters each
    trigemm_kernel<<<1000, 256, 0, stream>>>(Abf, Bt, C);
}

// Round 3
// 248.635 us; speedup vs baseline: 1.0429x; 1.0065x over previous
//
#include <hip/hip_runtime.h>
#include <hip/hip_bf16.h>
#include <stdint.h>

#define NDIM 4096
#define BM 128
#define BN 128
#define BK 32
#define LDSS 40   // LDS k-stride (shorts): BK+8 pad -> 80B rows, 16B-aligned, 2-way banks

typedef __attribute__((ext_vector_type(8))) short bf16x8;
typedef __attribute__((ext_vector_type(8))) unsigned short u16x8;
typedef __attribute__((ext_vector_type(4))) float f32x4;

__device__ __forceinline__ unsigned short f2bf(float f) {
    union { float f; uint32_t u; } v; v.f = f;
    uint32_t u = v.u;
    u += 0x7FFFu + ((u >> 16) & 1u);   // round-to-nearest-even
    return (unsigned short)(u >> 16);
}

// --- Fused prep kernel (unchanged from R2 as control) ---
// blocks [0,8192):      A (fp32) -> triu-masked bf16 row-major
// blocks [8192,16384):  B -> triu-masked bf16 transposed Bt[c][k]
// blocks [16384,32768): C zero-fill
__global__ __launch_bounds__(256) void prep_kernel(const float* __restrict__ A,
                                                   const float* __restrict__ B,
                                                   unsigned short* __restrict__ Abf,
                                                   unsigned short* __restrict__ Bt,
                                                   float* __restrict__ C) {
    __shared__ float lds[32 * 65];
    const int b   = blockIdx.x;
    const int tid = threadIdx.x;

    if (b < 8192) {
        int idx = (b * 256 + tid) * 8;
        int row = idx >> 12;
        int col = idx & 4095;
        float4 v0 = *(const float4*)(A + idx);
        float4 v1 = *(const float4*)(A + idx + 4);
        u16x8 o;
        o[0] = (col + 0 >= row) ? f2bf(v0.x) : (unsigned short)0;
        o[1] = (col + 1 >= row) ? f2bf(v0.y) : (unsigned short)0;
        o[2] = (col + 2 >= row) ? f2bf(v0.z) : (unsigned short)0;
        o[3] = (col + 3 >= row) ? f2bf(v0.w) : (unsigned short)0;
        o[4] = (col + 4 >= row) ? f2bf(v1.x) : (unsigned short)0;
        o[5] = (col + 5 >= row) ? f2bf(v1.y) : (unsigned short)0;
        o[6] = (col + 6 >= row) ? f2bf(v1.z) : (unsigned short)0;
        o[7] = (col + 7 >= row) ? f2bf(v1.w) : (unsigned short)0;
        *(u16x8*)(Abf + idx) = o;
    } else if (b < 16384) {
        int tb = b - 8192;
        int c0 = (tb & 127) * 32;
        int k0 = (tb >> 7) * 64;
        #pragma unroll
        for (int p = 0; p < 2; ++p) {
            int kr = p * 32 + (tid >> 3);
            int cc = (tid & 7) * 4;
            float4 v = *(const float4*)(B + (size_t)(k0 + kr) * NDIM + c0 + cc);
            lds[(cc + 0) * 65 + kr] = v.x;
            lds[(cc + 1) * 65 + kr] = v.y;
            lds[(cc + 2) * 65 + kr] = v.z;
            lds[(cc + 3) * 65 + kr] = v.w;
        }
        __syncthreads();
        int c  = tid >> 3;
        int ks = (tid & 7) * 8;
        u16x8 o;
        #pragma unroll
        for (int j = 0; j < 8; ++j) {
            float f = lds[c * 65 + ks + j];
            o[j] = (k0 + ks + j <= c0 + c) ? f2bf(f) : (unsigned short)0;
        }
        *(u16x8*)(Bt + (size_t)(c0 + c) * NDIM + k0 + ks) = o;
    } else {
        int idx = ((b - 16384) * 256 + tid) * 4;
        float4 z = {0.f, 0.f, 0.f, 0.f};
        *(float4*)(C + idx) = z;
    }
}

// --- Triangular bf16 MFMA GEMM, split-K (chunk <= 32 k-iters) ---
// R3: global->VGPR->ds_write pipeline. VGPR-destined loads are NOT drained at
// s_barrier (unlike global_load_lds); the vmcnt wait lands at next iter's
// ds_write, ~1 MFMA-phase after issue -> latency hidden across the barrier.
__global__ __launch_bounds__(256, 3) void trigemm_kernel(
        const unsigned short* __restrict__ Abf,
        const unsigned short* __restrict__ Bt,
        float* __restrict__ C) {
    // decode blockIdx -> (d, tile, split); d descending
    int rem = blockIdx.x;
    int d = 31, nsplit = 4;
    for (;; --d) {
        nsplit = (d + 8) >> 3;             // ceil((d+1)/8)
        int cnt = (32 - d) * nsplit;
        if (rem < cnt) break;
        rem -= cnt;
    }
    const int bi = rem / nsplit;
    const int split = rem - bi * nsplit;
    const int bj = bi + d;

    __shared__ unsigned short As[BM * LDSS];   // 10 KB
    __shared__ unsigned short Bs[BN * LDSS];   // 10 KB

    const int tid  = threadIdx.x;
    const int wave = tid >> 6, lane = tid & 63;
    const int wm = wave >> 1, wn = wave & 1;
    const int m_l = lane & 15, kh = lane >> 4;

    f32x4 acc[4][4] = {};

    const int i0 = bi * BM, j0 = bj * BN;
    const int kiters_tile = (d + 1) * 4;
    const int it0 = split * 32;
    int nit = kiters_tile - it0; if (nit > 32) nit = 32;
    const int k_start = i0 + it0 * BK;

    const unsigned short* Ar = Abf + (size_t)i0 * NDIM;
    const unsigned short* Br = Bt  + (size_t)j0 * NDIM;

    // staging map: thread covers rows r0 (=tid>>2) and r1 (=64+tid>>2), 8 k-elems at kc
    const int r0 = tid >> 2;
    const int r1 = 64 + (tid >> 2);
    const int kc = (tid & 3) * 8;

    u16x8 ra0, ra1, rb0, rb1;
    {
        const size_t o0 = (size_t)r0 * NDIM + k_start + kc;
        const size_t o1 = (size_t)r1 * NDIM + k_start + kc;
        ra0 = *(const u16x8*)(Ar + o0);
        ra1 = *(const u16x8*)(Ar + o1);
        rb0 = *(const u16x8*)(Br + o0);
        rb1 = *(const u16x8*)(Br + o1);
    }

    for (int it = 0; it < nit; ++it) {
        __syncthreads();   // previous iteration's ds_reads complete; LDS reusable
        *(u16x8*)&As[r0 * LDSS + kc] = ra0;   // vmcnt wait happens here (1 iter late)
        *(u16x8*)&As[r1 * LDSS + kc] = ra1;
        *(u16x8*)&Bs[r0 * LDSS + kc] = rb0;
        *(u16x8*)&Bs[r1 * LDSS + kc] = rb1;
        if (it + 1 < nit) {
            const int kn = k_start + (it + 1) * BK;
            const size_t o0 = (size_t)r0 * NDIM + kn + kc;
            const size_t o1 = (size_t)r1 * NDIM + kn + kc;
            ra0 = *(const u16x8*)(Ar + o0);   // in flight across the next barrier
            ra1 = *(const u16x8*)(Ar + o1);
            rb0 = *(const u16x8*)(Br + o0);
            rb1 = *(const u16x8*)(Br + o1);
        }
        __syncthreads();   // LDS filled (lgkmcnt-only wait)

        bf16x8 af[4], bfr[4];
        const unsigned short* pA = &As[(wm * 64 + m_l) * LDSS + kh * 8];
        const unsigned short* pB = &Bs[(wn * 64 + m_l) * LDSS + kh * 8];
        #pragma unroll
        for (int mt = 0; mt < 4; ++mt)
            af[mt] = *(const bf16x8*)(pA + mt * 16 * LDSS);
        #pragma unroll
        for (int nt = 0; nt < 4; ++nt)
            bfr[nt] = *(const bf16x8*)(pB + nt * 16 * LDSS);

        #pragma unroll
        for (int mt = 0; mt < 4; ++mt)
            #pragma unroll
            for (int nt = 0; nt < 4; ++nt)
                acc[mt][nt] = __builtin_amdgcn_mfma_f32_16x16x32_bf16(
                    af[mt], bfr[nt], acc[mt][nt], 0, 0, 0);
    }

    // Epilogue: C/D layout col=lane&15, row=(lane>>4)*4+reg (m89/m91-verified).
    // Inputs triu-masked -> below-diagonal accs are exactly 0; C pre-zeroed;
    // single-split tiles plain-store, multi-split atomicAdd.
    float* Crow = C + (size_t)i0 * NDIM + j0;
    const bool single = (nsplit == 1);
    #pragma unroll
    for (int mt = 0; mt < 4; ++mt) {
        #pragma unroll
        for (int nt = 0; nt < 4; ++nt) {
            #pragma unroll
            for (int r = 0; r < 4; ++r) {
                int row = wm * 64 + mt * 16 + kh * 4 + r;
                int col = wn * 64 + nt * 16 + m_l;
                float* p = Crow + (size_t)row * NDIM + col;
                if (single) *p = acc[mt][nt][r];
                else        atomicAdd(p, acc[mt][nt][r]);
            }
        }
    }
}

extern "C" void kernel_launch(void* const* d_in, const int* in_sizes, int n_in,
                              void* d_out, int out_size, void* d_ws, size_t ws_size,
                              hipStream_t stream) {
    const float* A = (const float*)d_in[0];
    const float* B = (const float*)d_in[1];
    float* C = (float*)d_out;

    unsigned short* Abf = (unsigned short*)d_ws;                   // 32 MB
    unsigned short* Bt  = Abf + (size_t)NDIM * NDIM;               // 32 MB

    prep_kernel<<<32768, 256, 0, stream>>>(A, B, Abf, Bt, C);
    trigemm_kernel<<<1000, 256, 0, stream>>>(Abf, Bt, C);
}

// Round 5
// 217.288 us; speedup vs baseline: 1.1933x; 1.1443x over previous
//
#include <hip/hip_runtime.h>
#include <hip/hip_bf16.h>
#include <stdint.h>

#define NDIM 4096
#define BM 128
#define BN 128
#define BK 64            // 8 chunks of 8 bf16 (16B vaults) per row

typedef __attribute__((ext_vector_type(8))) short bf16x8;
typedef __attribute__((ext_vector_type(8))) unsigned short u16x8;
typedef __attribute__((ext_vector_type(4))) float f32x4;   // native vec: ok for nontemporal builtins

__device__ __forceinline__ unsigned short f2bf(float f) {
    union { float f; uint32_t u; } v; v.f = f;
    uint32_t u = v.u;
    u += 0x7FFFu + ((u >> 16) & 1u);   // round-to-nearest-even
    return (unsigned short)(u >> 16);
}

// --- Fused prep kernel ---
// blocks [0,2048):    A (fp32) -> triu-masked bf16 row-major (8192 elems/block)
// blocks [2048,4096): B -> triu-masked bf16 transposed Bt[c][k] (64k x 128c per block)
__global__ __launch_bounds__(256) void prep_kernel(const float* __restrict__ A,
                                                   const float* __restrict__ B,
                                                   unsigned short* __restrict__ Abf,
                                                   unsigned short* __restrict__ Bt) {
    __shared__ float lds[32 * 65];
    const int b   = blockIdx.x;
    const int tid = threadIdx.x;

    if (b < 2048) {
        #pragma unroll
        for (int it = 0; it < 4; ++it) {
            int idx = b * 8192 + it * 2048 + tid * 8;
            int row = idx >> 12;
            int col = idx & 4095;
            f32x4 v0 = __builtin_nontemporal_load((const f32x4*)(A + idx));
            f32x4 v1 = __builtin_nontemporal_load((const f32x4*)(A + idx + 4));
            u16x8 o;
            o[0] = (col + 0 >= row) ? f2bf(v0.x) : (unsigned short)0;
            o[1] = (col + 1 >= row) ? f2bf(v0.y) : (unsigned short)0;
            o[2] = (col + 2 >= row) ? f2bf(v0.z) : (unsigned short)0;
            o[3] = (col + 3 >= row) ? f2bf(v0.w) : (unsigned short)0;
            o[4] = (col + 4 >= row) ? f2bf(v1.x) : (unsigned short)0;
            o[5] = (col + 5 >= row) ? f2bf(v1.y) : (unsigned short)0;
            o[6] = (col + 6 >= row) ? f2bf(v1.z) : (unsigned short)0;
            o[7] = (col + 7 >= row) ? f2bf(v1.w) : (unsigned short)0;
            *(u16x8*)(Abf + idx) = o;
        }
    } else {
        // B transpose+convert: block covers 64 k-rows x 128 c-cols as 4 sub-tiles
        int tb = b - 2048;
        int k0 = (tb >> 5) * 64;           // 64 k-groups
        int c0 = (tb & 31) * 128;          // 32 c-groups
        #pragma unroll
        for (int s = 0; s < 4; ++s) {
            int c0s = c0 + s * 32;
            #pragma unroll
            for (int p = 0; p < 2; ++p) {
                int kr = p * 32 + (tid >> 3);
                int cc = (tid & 7) * 4;
                f32x4 v = __builtin_nontemporal_load(
                    (const f32x4*)(B + (size_t)(k0 + kr) * NDIM + c0s + cc));
                lds[(cc + 0) * 65 + kr] = v.x;
                lds[(cc + 1) * 65 + kr] = v.y;
                lds[(cc + 2) * 65 + kr] = v.z;
                lds[(cc + 3) * 65 + kr] = v.w;
            }
            __syncthreads();
            int c  = tid >> 3;
            int ks = (tid & 7) * 8;
            u16x8 o;
            #pragma unroll
            for (int j = 0; j < 8; ++j) {
                float f = lds[c * 65 + ks + j];
                o[j] = (k0 + ks + j <= c0s + c) ? f2bf(f) : (unsigned short)0;
            }
            *(u16x8*)(Bt + (size_t)(c0s + c) * NDIM + k0 + ks) = o;
            __syncthreads();
        }
    }
}

// --- Triangular bf16 MFMA GEMM ---
// 528 upper tiles, d = bj-bi descending (longest-K first). BK=64, XOR-swizzled
// LDS (conflict-free writes, 2-way reads), depth-2 VGPR prefetch pipeline,
// plain nontemporal stores, mirror lower tile zero-filled by the same block.
__global__ __launch_bounds__(256, 2) void trigemm_kernel(
        const unsigned short* __restrict__ Abf,
        const unsigned short* __restrict__ Bt,
        float* __restrict__ C) {
    int rem = blockIdx.x, d = 31;
    while (rem >= 32 - d) { rem -= 32 - d; --d; }
    const int bi = rem, bj = bi + d;

    __shared__ unsigned short As[BM * BK];   // 16 KB
    __shared__ unsigned short Bs[BN * BK];   // 16 KB

    const int tid  = threadIdx.x;
    const int wave = tid >> 6, lane = tid & 63;
    const int wm = wave >> 1, wn = wave & 1;
    const int m_l = lane & 15, kh = lane >> 4;
    const int ml7 = m_l & 7;

    f32x4 acc[4][4] = {};

    const int i0 = bi * BM, j0 = bj * BN;
    const int nit = (d + 1) * 2;             // BK=64 iters; always even, >=2
    const int k_start = i0;

    const unsigned short* Ar = Abf + (size_t)i0 * NDIM;
    const unsigned short* Br = Bt  + (size_t)j0 * NDIM;

    // staging map: pass p covers row r0+32p, chunk kc (16B); xor depends only on r0&7
    const int r0 = tid >> 3, kc = tid & 7;
    const int woff = r0 * BK + ((kc ^ (r0 & 7)) * 8);       // LDS short idx, + p*2048
    const size_t g0 = (size_t)r0 * NDIM + kc * 8;           // + p*32*NDIM + koff

    u16x8 a0_0, a0_1, a0_2, a0_3, b0_0, b0_1, b0_2, b0_3;
    u16x8 a1_0, a1_1, a1_2, a1_3, b1_0, b1_1, b1_2, b1_3;

#define LOAD_STAGE(AN, BN_, koff) do {                                          \
        const size_t _g = g0 + (size_t)(koff);                                  \
        AN##_0 = *(const u16x8*)(Ar + _g);                                      \
        AN##_1 = *(const u16x8*)(Ar + _g + (size_t)32 * NDIM);                  \
        AN##_2 = *(const u16x8*)(Ar + _g + (size_t)64 * NDIM);                  \
        AN##_3 = *(const u16x8*)(Ar + _g + (size_t)96 * NDIM);                  \
        BN_##_0 = *(const u16x8*)(Br + _g);                                     \
        BN_##_1 = *(const u16x8*)(Br + _g + (size_t)32 * NDIM);                 \
        BN_##_2 = *(const u16x8*)(Br + _g + (size_t)64 * NDIM);                 \
        BN_##_3 = *(const u16x8*)(Br + _g + (size_t)96 * NDIM);                 \
    } while (0)

#define WRITE_STAGE(AN, BN_) do {                                               \
        *(u16x8*)&As[woff         ] = AN##_0;                                   \
        *(u16x8*)&As[woff + 1*2048] = AN##_1;                                   \
        *(u16x8*)&As[woff + 2*2048] = AN##_2;                                   \
        *(u16x8*)&As[woff + 3*2048] = AN##_3;                                   \
        *(u16x8*)&Bs[woff         ] = BN_##_0;                                  \
        *(u16x8*)&Bs[woff + 1*2048] = BN_##_1;                                  \
        *(u16x8*)&Bs[woff + 2*2048] = BN_##_2;                                  \
        *(u16x8*)&Bs[woff + 3*2048] = BN_##_3;                                  \
    } while (0)

#define COMPUTE() do {                                                          \
        _Pragma("unroll")                                                       \
        for (int s = 0; s < 2; ++s) {                                           \
            const int xk = ((s * 4 + kh) ^ ml7) * 8;                            \
            bf16x8 bfr[4], afr[4];                                              \
            _Pragma("unroll")                                                   \
            for (int nt = 0; nt < 4; ++nt)                                      \
                bfr[nt] = *(const bf16x8*)&Bs[(wn*64 + nt*16 + m_l)*BK + xk];   \
            _Pragma("unroll")                                                   \
            for (int mt = 0; mt < 4; ++mt)                                      \
                afr[mt] = *(const bf16x8*)&As[(wm*64 + mt*16 + m_l)*BK + xk];   \
            _Pragma("unroll")                                                   \
            for (int mt = 0; mt < 4; ++mt)                                      \
                _Pragma("unroll")                                               \
                for (int nt = 0; nt < 4; ++nt)                                  \
                    acc[mt][nt] = __builtin_amdgcn_mfma_f32_16x16x32_bf16(      \
                        afr[mt], bfr[nt], acc[mt][nt], 0, 0, 0);                \
        }                                                                       \
    } while (0)

    LOAD_STAGE(a0, b0, k_start);
    LOAD_STAGE(a1, b1, k_start + BK);

    for (int it = 0; it < nit; it += 2) {
        WRITE_STAGE(a0, b0);                 // vmcnt wait: loads issued 2 iters ago
        if (it + 2 < nit) LOAD_STAGE(a0, b0, k_start + (it + 2) * BK);
        __syncthreads();
        COMPUTE();
        __syncthreads();
        WRITE_STAGE(a1, b1);
        if (it + 3 < nit) LOAD_STAGE(a1, b1, k_start + (it + 3) * BK);
        __syncthreads();
        COMPUTE();
        __syncthreads();
    }
#undef LOAD_STAGE
#undef WRITE_STAGE
#undef COMPUTE

    // Epilogue: C/D layout col=lane&15, row=(lane>>4)*4+reg (m89/m91-verified).
    // Inputs triu-masked -> below-diagonal accs exactly 0; plain stores.
    float* Cbase = C + (size_t)i0 * NDIM + j0;
    #pragma unroll
    for (int mt = 0; mt < 4; ++mt) {
        #pragma unroll
        for (int nt = 0; nt < 4; ++nt) {
            #pragma unroll
            for (int r = 0; r < 4; ++r) {
                int row = wm * 64 + mt * 16 + kh * 4 + r;
                int col = wn * 64 + nt * 16 + m_l;
                __builtin_nontemporal_store(acc[mt][nt][r],
                                            Cbase + (size_t)row * NDIM + col);
            }
        }
    }
    // Mirror lower tile (bj,bi) zero-fill (C is 0xAA-poisoned each call)
    if (bi != bj) {
        float* Z = C + (size_t)j0 * NDIM + i0;
        f32x4 z = {0.f, 0.f, 0.f, 0.f};
        #pragma unroll
        for (int t = 0; t < 16; ++t) {
            int off = (t * 256 + tid) * 4;
            int rr = off >> 7, cc = off & 127;
            __builtin_nontemporal_store(z, (f32x4*)(Z + (size_t)rr * NDIM + cc));
        }
    }
}

extern "C" void kernel_launch(void* const* d_in, const int* in_sizes, int n_in,
                              void* d_out, int out_size, void* d_ws, size_t ws_size,
                              hipStream_t stream) {
    const float* A = (const float*)d_in[0];
    const float* B = (const float*)d_in[1];
    float* C = (float*)d_out;

    unsigned short* Abf = (unsigned short*)d_ws;                   // 32 MB
    unsigned short* Bt  = Abf + (size_t)NDIM * NDIM;               // 32 MB

    prep_kernel<<<4096, 256, 0, stream>>>(A, B, Abf, Bt);
    trigemm_kernel<<<528, 256, 0, stream>>>(Abf, Bt, C);
}